// Round 5
// baseline (50214.386 us; speedup 1.0000x reference)
//
#include <hip/hip_runtime.h>
#include <stdint.h>
#include <math.h>

#define Bn 32768
#define Ln 7
#define Tn 6
#define En 256
#define Hn 256
#define Rr 8
#define NEGF (-1000000000.0f)

// ---------------------------------------------------------------------------
// ws layout (floats):
//   [0, 7*65536)            : 7 transposed weight matrices WT[m][e][h]
//                             order: Wh, Wv, Wsh, Wsv, Wedge, Win, Wctx
//   [458752, 458752+B*7)    : att[b][l]
//   [688128, 688142)        : S[7], logS[7]
// ---------------------------------------------------------------------------

__device__ __forceinline__ uint32_t rotl32(uint32_t x, int d) {
  return (x << d) | (x >> (32 - d));
}

// JAX threefry2x32, 20 rounds (matches jax/_src/prng.py)
__device__ __forceinline__ void threefry2x32(uint32_t k0, uint32_t k1,
                                             uint32_t x0, uint32_t x1,
                                             uint32_t& o0, uint32_t& o1) {
  uint32_t k2 = k0 ^ k1 ^ 0x1BD11BDAu;
  x0 += k0; x1 += k1;
  x0 += x1; x1 = rotl32(x1, 13); x1 ^= x0;
  x0 += x1; x1 = rotl32(x1, 15); x1 ^= x0;
  x0 += x1; x1 = rotl32(x1, 26); x1 ^= x0;
  x0 += x1; x1 = rotl32(x1,  6); x1 ^= x0;
  x0 += k1; x1 += k2 + 1u;
  x0 += x1; x1 = rotl32(x1, 17); x1 ^= x0;
  x0 += x1; x1 = rotl32(x1, 29); x1 ^= x0;
  x0 += x1; x1 = rotl32(x1, 16); x1 ^= x0;
  x0 += x1; x1 = rotl32(x1, 24); x1 ^= x0;
  x0 += k2; x1 += k0 + 2u;
  x0 += x1; x1 = rotl32(x1, 13); x1 ^= x0;
  x0 += x1; x1 = rotl32(x1, 15); x1 ^= x0;
  x0 += x1; x1 = rotl32(x1, 26); x1 ^= x0;
  x0 += x1; x1 = rotl32(x1,  6); x1 ^= x0;
  x0 += k0; x1 += k1 + 3u;
  x0 += x1; x1 = rotl32(x1, 17); x1 ^= x0;
  x0 += x1; x1 = rotl32(x1, 29); x1 ^= x0;
  x0 += x1; x1 = rotl32(x1, 16); x1 ^= x0;
  x0 += x1; x1 = rotl32(x1, 24); x1 ^= x0;
  x0 += k1; x1 += k2 + 4u;
  x0 += x1; x1 = rotl32(x1, 13); x1 ^= x0;
  x0 += x1; x1 = rotl32(x1, 15); x1 ^= x0;
  x0 += x1; x1 = rotl32(x1, 26); x1 ^= x0;
  x0 += x1; x1 = rotl32(x1,  6); x1 ^= x0;
  x0 += k2; x1 += k0 + 5u;
  o0 = x0; o1 = x1;
}

// ---------------------------------------------------------------------------
// Transpose the 7 weight matrices (256x256 each) into ws.
// ---------------------------------------------------------------------------
__global__ __launch_bounds__(256) void k_transpose(
    const float* __restrict__ w0, const float* __restrict__ w1,
    const float* __restrict__ w2, const float* __restrict__ w3,
    const float* __restrict__ w4, const float* __restrict__ w5,
    const float* __restrict__ w6, float* __restrict__ dst) {
  const float* src;
  switch (blockIdx.y) {
    case 0: src = w0; break;
    case 1: src = w1; break;
    case 2: src = w2; break;
    case 3: src = w3; break;
    case 4: src = w4; break;
    case 5: src = w5; break;
    default: src = w6; break;
  }
  int e = blockIdx.x;       // grid.x = 256
  int h = threadIdx.x;      // 256 threads
  dst[(size_t)blockIdx.y * 65536 + e * 256 + h] = src[h * 256 + e];
}

// ---------------------------------------------------------------------------
// Main fused kernel: one WG (256 threads, thread = h channel) per 8 rows.
//
// ROUND-5 FIX: the persistent 27-93 GB of scratch traffic across rounds 1-4
// was the instruction SCHEDULER batching uniform (scalar-pipe) enc loads
// and offset loads across many (tt,r) chunks to hide latency -> hundreds
// of live SGPR/VGPR values -> spill at ANY register budget (even 256).
// Countermeasures:
//   * __builtin_amdgcn_sched_barrier(0) after every inner chunk and at the
//     end of every e0 iteration: scheduler window = one chunk (~16 values).
//   * volatile LDS reads of the offset pack: LICM cannot materialize the
//     80 hoisted offsets (IR-level hoisting that sched_barrier can't stop).
//   * with live set now bounded (~85), __launch_bounds__(256,2): 128-VGPR
//     budget, 3 blocks/CU (LDS-limited) = 3 waves/SIMD for latency hiding.
// enc reads stay GLOBAL UNIFORM (lower to s_load on the scalar pipe,
// parallel to VALU) — deliberately not LDS-staged (LDS-issue-bound).
//
// LDS: edges 40KB + qt 8KB + pack 320B + red 128B = 48.5KB -> 3 blocks/CU.
// ---------------------------------------------------------------------------
__global__ __launch_bounds__(256, 2) void k_main(
    const float* __restrict__ enc, const int* __restrict__ xes,
    const int* __restrict__ maskp, const float* __restrict__ wt,
    const float* __restrict__ b_in, const float* __restrict__ b_ctx,
    const float* __restrict__ V, float* __restrict__ att_out) {
  const int t = threadIdx.x;
  const int b0 = blockIdx.x * Rr;

  const float* WhT   = wt;
  const float* WvT   = wt + 65536;
  const float* WshT  = wt + 2 * 65536;
  const float* WsvT  = wt + 3 * 65536;
  const float* WeT   = wt + 4 * 65536;
  const float* WinT  = wt + 5 * 65536;
  const float* WctxT = wt + 6 * 65536;

  __shared__ int   s_pack[5 * Rr * 2];     // {offh|cond, offv} per (tt,r)
  __shared__ float s_edges[5 * Rr * 256];  // 40KB: edge_tt[r][t]
  __shared__ float s_qt[Rr * 256];         // 8KB: qt[r][t]
  __shared__ float s_red[4 * Rr];

  if (t < 5 * Rr) {
    int tt = t >> 3, r = t & 7;
    int base = ((b0 + r) * Tn + tt) * 3;
    int hi = xes[base], vi = xes[base + 1], tc = xes[base + 2];
    int oh = ((b0 + r) * Ln + hi) * En;   // multiple of 256 -> bit0 free
    int ov = ((b0 + r) * Ln + vi) * En;
    s_pack[t * 2]     = oh | ((tc == 0) ? 1 : 0);
    s_pack[t * 2 + 1] = ov;
  }
  __syncthreads();

  volatile const int* vp = s_pack;   // volatile: LICM cannot hoist these

  // ---- P1: edges for tt=0..4, acc[5][8], weights loaded once per e0 ----
  float acc[5][Rr];
#pragma unroll
  for (int i = 0; i < 5; i++)
#pragma unroll
    for (int r = 0; r < Rr; r++) acc[i][r] = 0.f;

#pragma unroll 1
  for (int e0 = 0; e0 < En; e0 += 8) {
    float wh[8], wv[8], wsh[8], wsv[8];
#pragma unroll
    for (int j = 0; j < 8; j++) {
      int o = (e0 + j) * 256 + t;
      wh[j] = WhT[o]; wv[j] = WvT[o]; wsh[j] = WshT[o]; wsv[j] = WsvT[o];
    }
#pragma unroll
    for (int tt = 0; tt < 5; tt++) {
#pragma unroll
      for (int r = 0; r < Rr; r++) {
        int w0 = __builtin_amdgcn_readfirstlane(vp[(tt * Rr + r) * 2]);
        int w1 = __builtin_amdgcn_readfirstlane(vp[(tt * Rr + r) * 2 + 1]);
        int cond = w0 & 1;
        const float* __restrict__ ph = enc + (w0 - cond) + e0;
        const float* __restrict__ pv = enc + w1 + e0;
        float a = acc[tt][r];
        if (cond) {
#pragma unroll
          for (int j = 0; j < 8; j++) a += wh[j] * ph[j] + wv[j] * pv[j];
        } else {
#pragma unroll
          for (int j = 0; j < 8; j++) a += wsh[j] * ph[j] + wsv[j] * pv[j];
        }
        acc[tt][r] = a;
        __builtin_amdgcn_sched_barrier(0);   // scheduler window = 1 chunk
      }
    }
    __builtin_amdgcn_sched_barrier(0);       // no cross-iteration batching
  }

  // stage edges to LDS (lane-consecutive -> conflict-free)
#pragma unroll
  for (int tt = 0; tt < 5; tt++)
#pragma unroll
    for (int r = 0; r < Rr; r++)
      s_edges[(tt * Rr + r) * 256 + t] = acc[tt][r];
  __syncthreads();

  // ---- P2: m[tt][r] = (edge_tt @ We^T)[r][t], single WeT pass ----------
  float m[5][Rr];
#pragma unroll
  for (int i = 0; i < 5; i++)
#pragma unroll
    for (int r = 0; r < Rr; r++) m[i][r] = 0.f;

#pragma unroll 1
  for (int e0 = 0; e0 < En; e0 += 8) {
    float w8[8];
#pragma unroll
    for (int j = 0; j < 8; j++) w8[j] = WeT[(e0 + j) * 256 + t];
#pragma unroll
    for (int tt = 0; tt < 5; tt++) {
#pragma unroll
      for (int r = 0; r < Rr; r++) {
        const float* xb = &s_edges[(tt * Rr + r) * 256 + e0];  // uniform
        float4 xa = *(const float4*)(xb);
        float4 xc = *(const float4*)(xb + 4);
        float s = m[tt][r];
        s += w8[0] * xa.x; s += w8[1] * xa.y;
        s += w8[2] * xa.z; s += w8[3] * xa.w;
        s += w8[4] * xc.x; s += w8[5] * xc.y;
        s += w8[6] * xc.z; s += w8[7] * xc.w;
        m[tt][r] = s;
        __builtin_amdgcn_sched_barrier(0);
      }
    }
    __builtin_amdgcn_sched_barrier(0);
  }

  // ---- P3: st = max(0, max_tt m); qt = relu(edge4 + st) ----------------
#pragma unroll
  for (int r = 0; r < Rr; r++) {
    float s = fmaxf(fmaxf(fmaxf(m[0][r], m[1][r]), fmaxf(m[2][r], m[3][r])),
                    m[4][r]);
    s = fmaxf(s, 0.f);
    float e4 = s_edges[(4 * Rr + r) * 256 + t];   // per-lane, own t
    s_qt[r * 256 + t] = fmaxf(e4 + s, 0.f);
  }
  __syncthreads();

  // ---- P4: inp[r] = qt[r] @ Win^T + b_in (at own t) --------------------
  float inp[Rr];
#pragma unroll
  for (int r = 0; r < Rr; r++) inp[r] = 0.f;
#pragma unroll 1
  for (int e0 = 0; e0 < En; e0 += 8) {
    float w8[8];
#pragma unroll
    for (int j = 0; j < 8; j++) w8[j] = WinT[(e0 + j) * 256 + t];
#pragma unroll
    for (int r = 0; r < Rr; r++) {
      const float* xb = &s_qt[r * 256 + e0];      // uniform
      float4 xa = *(const float4*)(xb);
      float4 xc = *(const float4*)(xb + 4);
      float s = inp[r];
      s += w8[0] * xa.x; s += w8[1] * xa.y;
      s += w8[2] * xa.z; s += w8[3] * xa.w;
      s += w8[4] * xc.x; s += w8[5] * xc.y;
      s += w8[6] * xc.z; s += w8[7] * xc.w;
      inp[r] = s;
      __builtin_amdgcn_sched_barrier(0);
    }
    __builtin_amdgcn_sched_barrier(0);
  }
  {
    float bi = b_in[t];
#pragma unroll
    for (int r = 0; r < Rr; r++) inp[r] += bi;
  }

  // ---- P5+P6: per l: cx[8] = enc[b,l,:]@Wctx^T; fused att reduce -------
  const float Vt = V[t];
  const float bc = b_ctx[t];
  const int lane = t & 63, wid = t >> 6;

#pragma unroll 1
  for (int l = 0; l < Ln; l++) {
    float cx[Rr];
#pragma unroll
    for (int r = 0; r < Rr; r++) cx[r] = 0.f;

#pragma unroll 1
    for (int e0 = 0; e0 < En; e0 += 8) {
      float w8[8];
#pragma unroll
      for (int j = 0; j < 8; j++) w8[j] = WctxT[(e0 + j) * 256 + t];
#pragma unroll
      for (int r = 0; r < Rr; r++) {
        const float* __restrict__ px = enc + ((b0 + r) * Ln + l) * En + e0;
        float c = cx[r];
#pragma unroll
        for (int j = 0; j < 8; j++) c += w8[j] * px[j];
        cx[r] = c;
        __builtin_amdgcn_sched_barrier(0);
      }
      __builtin_amdgcn_sched_barrier(0);
    }

    float v8[Rr];
#pragma unroll
    for (int r = 0; r < Rr; r++) v8[r] = Vt * tanhf(inp[r] + bc + cx[r]);
#pragma unroll
    for (int off = 32; off > 0; off >>= 1) {
#pragma unroll
      for (int r = 0; r < Rr; r++) v8[r] += __shfl_down(v8[r], off, 64);
    }
    if (lane == 0) {
#pragma unroll
      for (int r = 0; r < Rr; r++) s_red[wid * Rr + r] = v8[r];
    }
    __syncthreads();
    if (t < Rr) {
      float a = s_red[t] + s_red[Rr + t] + s_red[2 * Rr + t] +
                s_red[3 * Rr + t];
      int b = b0 + t;
      if (!maskp[b * Ln + l]) a = NEGF;
      a = 10.f * tanhf(a);
      att_out[b * Ln + l] = a;
    }
    __syncthreads();
  }
}

// ---------------------------------------------------------------------------
// Column sums for softmax over axis 0 (fp64 accumulation).
// ---------------------------------------------------------------------------
__global__ __launch_bounds__(256) void k_colsum(const float* __restrict__ att,
                                                float* __restrict__ sbuf) {
  int l = blockIdx.x;     // 0..6
  int t = threadIdx.x;
  double s = 0.0;
  for (int b = t; b < Bn; b += 256) s += exp((double)att[b * Ln + l]);
  __shared__ double sd[256];
  sd[t] = s;
  __syncthreads();
  for (int k = 128; k > 0; k >>= 1) {
    if (t < k) sd[t] += sd[t + k];
    __syncthreads();
  }
  if (t == 0) {
    sbuf[l] = (float)sd[0];
    sbuf[7 + l] = (float)log(sd[0]);
  }
}

// ---------------------------------------------------------------------------
// Gumbel-argmax sampling (threefry, partitionable bit-stream) + outputs.
// out = [idx(B) | p(B) | new_mask(B*7)] as float32.
// ---------------------------------------------------------------------------
__global__ __launch_bounds__(256) void k_sample(const float* __restrict__ att,
                                                const float* __restrict__ sbuf,
                                                const int* __restrict__ maskp,
                                                float* __restrict__ out) {
  int b = blockIdx.x * 256 + threadIdx.x;
  if (b >= Bn) return;
  float best = -3.0e38f;
  int bi = 0;
#pragma unroll
  for (int l = 0; l < Ln; l++) {
    uint32_t n = (uint32_t)(b * Ln + l);
    uint32_t o0, o1;
    threefry2x32(0u, 42u, 0u, n, o0, o1);   // counts64 = n -> (hi=0, lo=n)
    uint32_t bits = o0 ^ o1;                 // partitionable 32-bit fold
    uint32_t fb = (bits >> 9) | 0x3f800000u;
    float f = __uint_as_float(fb) - 1.0f;
    float u = fmaxf(f, 1.1754943508222875e-38f);
    float g = -logf(-logf(u));
    float y = att[b * Ln + l] - sbuf[7 + l] + g;
    if (y > best) { best = y; bi = l; }
  }
  out[b] = (float)bi;
  out[Bn + b] = expf(att[b * Ln + bi] - sbuf[7 + bi]);
#pragma unroll
  for (int l = 0; l < Ln; l++)
    out[2 * Bn + b * Ln + l] = (float)(maskp[b * Ln + l] - ((l == bi) ? 1 : 0));
}

// ---------------------------------------------------------------------------
extern "C" void kernel_launch(void* const* d_in, const int* in_sizes, int n_in,
                              void* d_out, int out_size, void* d_ws,
                              size_t ws_size, hipStream_t stream) {
  const float* enc   = (const float*)d_in[0];
  const int*   xes   = (const int*)d_in[1];
  const int*   maskp = (const int*)d_in[2];
  const float* W_h   = (const float*)d_in[3];
  const float* W_v   = (const float*)d_in[4];
  const float* Ws_h  = (const float*)d_in[5];
  const float* Ws_v  = (const float*)d_in[6];
  const float* W_e   = (const float*)d_in[7];
  const float* W_in  = (const float*)d_in[8];
  const float* b_in  = (const float*)d_in[9];
  const float* W_ctx = (const float*)d_in[10];
  const float* b_ctx = (const float*)d_in[11];
  const float* V     = (const float*)d_in[12];

  float* ws   = (float*)d_ws;
  float* wt   = ws;                   // 7*65536 floats
  float* att  = ws + 7 * 65536;       // B*7 floats
  float* sbuf = att + Bn * Ln;        // 14 floats

  dim3 gT(256, 7);
  k_transpose<<<gT, 256, 0, stream>>>(W_h, W_v, Ws_h, Ws_v, W_e, W_in, W_ctx, wt);
  k_main<<<Bn / Rr, 256, 0, stream>>>(enc, xes, maskp, wt, b_in, b_ctx, V, att);
  k_colsum<<<7, 256, 0, stream>>>(att, sbuf);
  k_sample<<<Bn / 256, 256, 0, stream>>>(att, sbuf, maskp, (float*)d_out);
}

// Round 6
// 36994.711 us; speedup vs baseline: 1.3573x; 1.3573x over previous
//
#include <hip/hip_runtime.h>
#include <stdint.h>
#include <math.h>

#define Bn 32768
#define Ln 7
#define Tn 6
#define En 256
#define Hn 256
#define NEGF (-1000000000.0f)

// chunking: process b in 8 chunks of 4096 to keep workspace ~32 MB
#define NCH 8
#define NBc (Bn / NCH)          // 4096 b per chunk
#define PPB 16                  // pairs per block in k_edge
#define RB2 8                   // b per block in k_stqt (40 E-rows)
#define RB3 16                  // b per block in k_inp
#define RB4 16                  // b per block in k_att

// ---------------------------------------------------------------------------
// ws layout (floats):
//   [0, 458752)          : 7 transposed weights WT[m][e][h] (Wh,Wv,Wsh,Wsv,We,Win,Wctx)
//   [458752, 688128)     : att[b][l]  (full B)
//   [688128, 688142)     : S[7], logS[7]
//   [688144, 5931024)    : Ec  — edge chunk, (NBc*5) x 256
//   [5931024, 6979600)   : qtc — qt chunk,  NBc x 256
//   [6979600, 8028176)   : inpc — inp chunk, NBc x 256
// total ~32.1 MB
// ---------------------------------------------------------------------------

__device__ __forceinline__ uint32_t rotl32(uint32_t x, int d) {
  return (x << d) | (x >> (32 - d));
}

// JAX threefry2x32, 20 rounds (matches jax/_src/prng.py)
__device__ __forceinline__ void threefry2x32(uint32_t k0, uint32_t k1,
                                             uint32_t x0, uint32_t x1,
                                             uint32_t& o0, uint32_t& o1) {
  uint32_t k2 = k0 ^ k1 ^ 0x1BD11BDAu;
  x0 += k0; x1 += k1;
  x0 += x1; x1 = rotl32(x1, 13); x1 ^= x0;
  x0 += x1; x1 = rotl32(x1, 15); x1 ^= x0;
  x0 += x1; x1 = rotl32(x1, 26); x1 ^= x0;
  x0 += x1; x1 = rotl32(x1,  6); x1 ^= x0;
  x0 += k1; x1 += k2 + 1u;
  x0 += x1; x1 = rotl32(x1, 17); x1 ^= x0;
  x0 += x1; x1 = rotl32(x1, 29); x1 ^= x0;
  x0 += x1; x1 = rotl32(x1, 16); x1 ^= x0;
  x0 += x1; x1 = rotl32(x1, 24); x1 ^= x0;
  x0 += k2; x1 += k0 + 2u;
  x0 += x1; x1 = rotl32(x1, 13); x1 ^= x0;
  x0 += x1; x1 = rotl32(x1, 15); x1 ^= x0;
  x0 += x1; x1 = rotl32(x1, 26); x1 ^= x0;
  x0 += x1; x1 = rotl32(x1,  6); x1 ^= x0;
  x0 += k0; x1 += k1 + 3u;
  x0 += x1; x1 = rotl32(x1, 17); x1 ^= x0;
  x0 += x1; x1 = rotl32(x1, 29); x1 ^= x0;
  x0 += x1; x1 = rotl32(x1, 16); x1 ^= x0;
  x0 += x1; x1 = rotl32(x1, 24); x1 ^= x0;
  x0 += k1; x1 += k2 + 4u;
  x0 += x1; x1 = rotl32(x1, 13); x1 ^= x0;
  x0 += x1; x1 = rotl32(x1, 15); x1 ^= x0;
  x0 += x1; x1 = rotl32(x1, 26); x1 ^= x0;
  x0 += x1; x1 = rotl32(x1,  6); x1 ^= x0;
  x0 += k2; x1 += k0 + 5u;
  o0 = x0; o1 = x1;
}

// ---------------------------------------------------------------------------
// Transpose the 7 weight matrices (256x256 each) into ws.
// ---------------------------------------------------------------------------
__global__ __launch_bounds__(256) void k_transpose(
    const float* __restrict__ w0, const float* __restrict__ w1,
    const float* __restrict__ w2, const float* __restrict__ w3,
    const float* __restrict__ w4, const float* __restrict__ w5,
    const float* __restrict__ w6, float* __restrict__ dst) {
  const float* src;
  switch (blockIdx.y) {
    case 0: src = w0; break;
    case 1: src = w1; break;
    case 2: src = w2; break;
    case 3: src = w3; break;
    case 4: src = w4; break;
    case 5: src = w5; break;
    default: src = w6; break;
  }
  int e = blockIdx.x;
  int h = threadIdx.x;
  dst[(size_t)blockIdx.y * 65536 + e * 256 + h] = src[h * 256 + e];
}

// ---------------------------------------------------------------------------
// k_edge: edges for PPB (b,tt) pairs per block (tt=0..4 only).
// Gather happens ONCE at cooperative LDS staging; the hot loop reads x via
// uniform LDS broadcasts (no loop-invariant global pointers to hoist).
// Live set: acc[16] + 32 weight regs + 16 transient x ~ 70 VGPR.
// ---------------------------------------------------------------------------
__global__ __launch_bounds__(256, 2) void k_edge(
    const float* __restrict__ enc, const int* __restrict__ xes,
    const float* __restrict__ wt, int bbase, float* __restrict__ Eo) {
  const int t = threadIdx.x;
  const int pg0 = blockIdx.x * PPB;      // chunk-local pair base

  __shared__ float x[PPB][2][256];       // 32 KB
  __shared__ int s_off[PPB][2];
  __shared__ int s_cond[PPB];

  if (t < PPB) {
    int pg = pg0 + t;
    int bl = pg / 5;
    int tt = pg - bl * 5;
    int b = bbase + bl;
    int base = (b * Tn + tt) * 3;
    int hi = xes[base], vi = xes[base + 1], tc = xes[base + 2];
    s_off[t][0] = (b * Ln + hi) * En;
    s_off[t][1] = (b * Ln + vi) * En;
    s_cond[t] = (tc == 0) ? 1 : 0;
  }
  __syncthreads();

  // cooperative stage: 32 rows, 8 threads/row, 8 float4 each (128B groups)
  {
    int seg = t >> 3, i8 = t & 7;        // seg 0..31
    int p = seg >> 1, w = seg & 1;
    const float* src = enc + s_off[p][w];
    float* dstrow = &x[p][w][0];
#pragma unroll
    for (int q = 0; q < 8; q++)
      *(float4*)&dstrow[i8 * 4 + q * 32] = *(const float4*)&src[i8 * 4 + q * 32];
  }
  __syncthreads();

  int cp[PPB];
#pragma unroll
  for (int p = 0; p < PPB; p++)
    cp[p] = __builtin_amdgcn_readfirstlane(s_cond[p]);

  const float* WhT  = wt;
  const float* WvT  = wt + 65536;
  const float* WshT = wt + 2 * 65536;
  const float* WsvT = wt + 3 * 65536;

  float acc[PPB];
#pragma unroll
  for (int p = 0; p < PPB; p++) acc[p] = 0.f;

#pragma unroll 1
  for (int e0 = 0; e0 < En; e0 += 8) {
    float wh[8], wv[8], ws1[8], ws2[8];
#pragma unroll
    for (int j = 0; j < 8; j++) {
      int o = (e0 + j) * 256 + t;
      wh[j] = WhT[o]; wv[j] = WvT[o]; ws1[j] = WshT[o]; ws2[j] = WsvT[o];
    }
#pragma unroll
    for (int p = 0; p < PPB; p++) {
      float4 h0 = *(const float4*)&x[p][0][e0];
      float4 h1 = *(const float4*)&x[p][0][e0 + 4];
      float4 v0 = *(const float4*)&x[p][1][e0];
      float4 v1 = *(const float4*)&x[p][1][e0 + 4];
      float a = acc[p];
      if (cp[p]) {
        a += wh[0]*h0.x; a += wh[1]*h0.y; a += wh[2]*h0.z; a += wh[3]*h0.w;
        a += wh[4]*h1.x; a += wh[5]*h1.y; a += wh[6]*h1.z; a += wh[7]*h1.w;
        a += wv[0]*v0.x; a += wv[1]*v0.y; a += wv[2]*v0.z; a += wv[3]*v0.w;
        a += wv[4]*v1.x; a += wv[5]*v1.y; a += wv[6]*v1.z; a += wv[7]*v1.w;
      } else {
        a += ws1[0]*h0.x; a += ws1[1]*h0.y; a += ws1[2]*h0.z; a += ws1[3]*h0.w;
        a += ws1[4]*h1.x; a += ws1[5]*h1.y; a += ws1[6]*h1.z; a += ws1[7]*h1.w;
        a += ws2[0]*v0.x; a += ws2[1]*v0.y; a += ws2[2]*v0.z; a += ws2[3]*v0.w;
        a += ws2[4]*v1.x; a += ws2[5]*v1.y; a += ws2[6]*v1.z; a += ws2[7]*v1.w;
      }
      acc[p] = a;
    }
  }

#pragma unroll
  for (int p = 0; p < PPB; p++)
    Eo[(pg0 + p) * 256 + t] = acc[p];
}

// ---------------------------------------------------------------------------
// k_stqt: M = E @ We^T for 40 rows (8 b x 5 tt); epilogue st/qt.
// Live: m[5][8]=40 + w8 + transients ~ 60 VGPR.
// ---------------------------------------------------------------------------
__global__ __launch_bounds__(256, 2) void k_stqt(
    const float* __restrict__ E, const float* __restrict__ wt,
    float* __restrict__ qt) {
  const int t = threadIdx.x;
  const int bl0 = blockIdx.x * RB2;

  __shared__ float xe[RB2 * 5][256];     // 40 KB

  {
    const float4* src = (const float4*)(E + bl0 * 5 * 256);
    float4* dst = (float4*)&xe[0][0];
#pragma unroll
    for (int k = 0; k < 10; k++) dst[t + k * 256] = src[t + k * 256];
  }
  __syncthreads();

  const float* WeT = wt + 4 * 65536;
  float m[5][RB2];
#pragma unroll
  for (int i = 0; i < 5; i++)
#pragma unroll
    for (int r = 0; r < RB2; r++) m[i][r] = 0.f;

#pragma unroll 1
  for (int e0 = 0; e0 < En; e0 += 8) {
    float w8[8];
#pragma unroll
    for (int j = 0; j < 8; j++) w8[j] = WeT[(e0 + j) * 256 + t];
#pragma unroll
    for (int tt = 0; tt < 5; tt++) {
#pragma unroll
      for (int r = 0; r < RB2; r++) {
        const float* xb = &xe[r * 5 + tt][e0];
        float4 xa = *(const float4*)(xb);
        float4 xc = *(const float4*)(xb + 4);
        float s = m[tt][r];
        s += w8[0]*xa.x; s += w8[1]*xa.y; s += w8[2]*xa.z; s += w8[3]*xa.w;
        s += w8[4]*xc.x; s += w8[5]*xc.y; s += w8[6]*xc.z; s += w8[7]*xc.w;
        m[tt][r] = s;
      }
    }
  }

#pragma unroll
  for (int r = 0; r < RB2; r++) {
    float s = fmaxf(fmaxf(fmaxf(m[0][r], m[1][r]), fmaxf(m[2][r], m[3][r])),
                    m[4][r]);
    s = fmaxf(s, 0.f);
    float e4 = xe[r * 5 + 4][t];         // per-lane, own t
    qt[(bl0 + r) * 256 + t] = fmaxf(e4 + s, 0.f);
  }
}

// ---------------------------------------------------------------------------
// k_inp: inp = qt @ Win^T + b_in for RB3 b's. Live ~ 40 VGPR.
// ---------------------------------------------------------------------------
__global__ __launch_bounds__(256, 2) void k_inp(
    const float* __restrict__ qt, const float* __restrict__ wt,
    const float* __restrict__ b_in, float* __restrict__ inp) {
  const int t = threadIdx.x;
  const int bl0 = blockIdx.x * RB3;

  __shared__ float xq[RB3][256];         // 16 KB
  {
    const float4* src = (const float4*)(qt + bl0 * 256);
    float4* dst = (float4*)&xq[0][0];
#pragma unroll
    for (int k = 0; k < 4; k++) dst[t + k * 256] = src[t + k * 256];
  }
  __syncthreads();

  const float* WinT = wt + 5 * 65536;
  float a[RB3];
#pragma unroll
  for (int r = 0; r < RB3; r++) a[r] = 0.f;

#pragma unroll 1
  for (int e0 = 0; e0 < En; e0 += 8) {
    float w8[8];
#pragma unroll
    for (int j = 0; j < 8; j++) w8[j] = WinT[(e0 + j) * 256 + t];
#pragma unroll
    for (int r = 0; r < RB3; r++) {
      const float* xb = &xq[r][e0];
      float4 xa = *(const float4*)(xb);
      float4 xc = *(const float4*)(xb + 4);
      float s = a[r];
      s += w8[0]*xa.x; s += w8[1]*xa.y; s += w8[2]*xa.z; s += w8[3]*xa.w;
      s += w8[4]*xc.x; s += w8[5]*xc.y; s += w8[6]*xc.z; s += w8[7]*xc.w;
      a[r] = s;
    }
  }
  float bi = b_in[t];
#pragma unroll
  for (int r = 0; r < RB3; r++)
    inp[(bl0 + r) * 256 + t] = a[r] + bi;
}

// ---------------------------------------------------------------------------
// k_att: per l: ctx = enc[b,l,:] @ Wctx^T; att = sum_h V*tanh(inp+b_ctx+ctx),
// mask, 10*tanh. RB4 b's per block. Live: cx[16]+ip[16]+w8 ~ 56 VGPR.
// ---------------------------------------------------------------------------
__global__ __launch_bounds__(256, 2) void k_att(
    const float* __restrict__ enc, const float* __restrict__ inp,
    const int* __restrict__ maskp, const float* __restrict__ wt,
    const float* __restrict__ b_ctx, const float* __restrict__ V,
    int bbase, float* __restrict__ att_out) {
  const int t = threadIdx.x;
  const int bl0 = blockIdx.x * RB4;

  __shared__ float xc[RB4][256];         // 16 KB
  __shared__ float red[4][RB4];

  float ip[RB4];
#pragma unroll
  for (int r = 0; r < RB4; r++) ip[r] = inp[(bl0 + r) * 256 + t];

  const float* WctxT = wt + 6 * 65536;
  const float Vt = V[t];
  const float bc = b_ctx[t];
  const int lane = t & 63, wid = t >> 6;

#pragma unroll 1
  for (int l = 0; l < Ln; l++) {
    // stage 16 enc rows for this l: 16 threads/row, 4 float4 each
    {
      int seg = t >> 4, i16 = t & 15;
      const float* src = enc + ((size_t)(bbase + bl0 + seg) * Ln + l) * En;
      float* dstrow = &xc[seg][0];
#pragma unroll
      for (int q = 0; q < 4; q++)
        *(float4*)&dstrow[i16 * 4 + q * 64] =
            *(const float4*)&src[i16 * 4 + q * 64];
    }
    __syncthreads();

    float cx[RB4];
#pragma unroll
    for (int r = 0; r < RB4; r++) cx[r] = 0.f;

#pragma unroll 1
    for (int e0 = 0; e0 < En; e0 += 8) {
      float w8[8];
#pragma unroll
      for (int j = 0; j < 8; j++) w8[j] = WctxT[(e0 + j) * 256 + t];
#pragma unroll
      for (int r = 0; r < RB4; r++) {
        const float* xb = &xc[r][e0];
        float4 xa = *(const float4*)(xb);
        float4 xq = *(const float4*)(xb + 4);
        float s = cx[r];
        s += w8[0]*xa.x; s += w8[1]*xa.y; s += w8[2]*xa.z; s += w8[3]*xa.w;
        s += w8[4]*xq.x; s += w8[5]*xq.y; s += w8[6]*xq.z; s += w8[7]*xq.w;
        cx[r] = s;
      }
    }

    float v8[RB4];
#pragma unroll
    for (int r = 0; r < RB4; r++) v8[r] = Vt * tanhf(ip[r] + bc + cx[r]);
#pragma unroll
    for (int off = 32; off > 0; off >>= 1) {
#pragma unroll
      for (int r = 0; r < RB4; r++) v8[r] += __shfl_down(v8[r], off, 64);
    }
    if (lane == 0) {
#pragma unroll
      for (int r = 0; r < RB4; r++) red[wid][r] = v8[r];
    }
    __syncthreads();   // red ready; all xc reads for this l done
    if (t < RB4) {
      float a = red[0][t] + red[1][t] + red[2][t] + red[3][t];
      int b = bbase + bl0 + t;
      if (!maskp[b * Ln + l]) a = NEGF;
      a = 10.f * tanhf(a);
      att_out[b * Ln + l] = a;
    }
    __syncthreads();   // att writers done before next l restages xc? (red only) — keeps phases clean
  }
}

// ---------------------------------------------------------------------------
// Column sums for softmax over axis 0 (fp64 accumulation).
// ---------------------------------------------------------------------------
__global__ __launch_bounds__(256) void k_colsum(const float* __restrict__ att,
                                                float* __restrict__ sbuf) {
  int l = blockIdx.x;
  int t = threadIdx.x;
  double s = 0.0;
  for (int b = t; b < Bn; b += 256) s += exp((double)att[b * Ln + l]);
  __shared__ double sd[256];
  sd[t] = s;
  __syncthreads();
  for (int k = 128; k > 0; k >>= 1) {
    if (t < k) sd[t] += sd[t + k];
    __syncthreads();
  }
  if (t == 0) {
    sbuf[l] = (float)sd[0];
    sbuf[7 + l] = (float)log(sd[0]);
  }
}

// ---------------------------------------------------------------------------
// Gumbel-argmax sampling (threefry, partitionable bit-stream) + outputs.
// out = [idx(B) | p(B) | new_mask(B*7)] as float32.
// ---------------------------------------------------------------------------
__global__ __launch_bounds__(256) void k_sample(const float* __restrict__ att,
                                                const float* __restrict__ sbuf,
                                                const int* __restrict__ maskp,
                                                float* __restrict__ out) {
  int b = blockIdx.x * 256 + threadIdx.x;
  if (b >= Bn) return;
  float best = -3.0e38f;
  int bi = 0;
#pragma unroll
  for (int l = 0; l < Ln; l++) {
    uint32_t n = (uint32_t)(b * Ln + l);
    uint32_t o0, o1;
    threefry2x32(0u, 42u, 0u, n, o0, o1);
    uint32_t bits = o0 ^ o1;
    uint32_t fb = (bits >> 9) | 0x3f800000u;
    float f = __uint_as_float(fb) - 1.0f;
    float u = fmaxf(f, 1.1754943508222875e-38f);
    float g = -logf(-logf(u));
    float y = att[b * Ln + l] - sbuf[7 + l] + g;
    if (y > best) { best = y; bi = l; }
  }
  out[b] = (float)bi;
  out[Bn + b] = expf(att[b * Ln + bi] - sbuf[7 + bi]);
#pragma unroll
  for (int l = 0; l < Ln; l++)
    out[2 * Bn + b * Ln + l] = (float)(maskp[b * Ln + l] - ((l == bi) ? 1 : 0));
}

// ---------------------------------------------------------------------------
extern "C" void kernel_launch(void* const* d_in, const int* in_sizes, int n_in,
                              void* d_out, int out_size, void* d_ws,
                              size_t ws_size, hipStream_t stream) {
  const float* enc   = (const float*)d_in[0];
  const int*   xes   = (const int*)d_in[1];
  const int*   maskp = (const int*)d_in[2];
  const float* W_h   = (const float*)d_in[3];
  const float* W_v   = (const float*)d_in[4];
  const float* Ws_h  = (const float*)d_in[5];
  const float* Ws_v  = (const float*)d_in[6];
  const float* W_e   = (const float*)d_in[7];
  const float* W_in  = (const float*)d_in[8];
  const float* b_in  = (const float*)d_in[9];
  const float* W_ctx = (const float*)d_in[10];
  const float* b_ctx = (const float*)d_in[11];
  const float* V     = (const float*)d_in[12];

  float* ws   = (float*)d_ws;
  float* wt   = ws;                         // 458752
  float* att  = ws + 458752;                // 229376
  float* sbuf = ws + 688128;                // 14 (pad to 688144)
  float* Ec   = ws + 688144;                // NBc*5*256 = 5242880
  float* qtc  = ws + 5931024;               // NBc*256 = 1048576
  float* inpc = ws + 6979600;               // NBc*256 = 1048576

  dim3 gT(256, 7);
  k_transpose<<<gT, 256, 0, stream>>>(W_h, W_v, Ws_h, Ws_v, W_e, W_in, W_ctx, wt);

  for (int c = 0; c < NCH; c++) {
    int bbase = c * NBc;
    k_edge<<<NBc * 5 / PPB, 256, 0, stream>>>(enc, xes, wt, bbase, Ec);
    k_stqt<<<NBc / RB2, 256, 0, stream>>>(Ec, wt, qtc);
    k_inp<<<NBc / RB3, 256, 0, stream>>>(qtc, wt, b_in, inpc);
    k_att<<<NBc / RB4, 256, 0, stream>>>(enc, inpc, maskp, wt, b_ctx, V,
                                         bbase, att);
  }

  k_colsum<<<7, 256, 0, stream>>>(att, sbuf);
  k_sample<<<Bn / 256, 256, 0, stream>>>(att, sbuf, maskp, (float*)d_out);
}

// Round 7
// 4443.142 us; speedup vs baseline: 11.3015x; 8.3262x over previous
//
#include <hip/hip_runtime.h>
#include <stdint.h>
#include <math.h>

#define Bn 32768
#define Ln 7
#define Tn 6
#define En 256
#define Hn 256
#define NEGF (-1000000000.0f)

// chunking: process b in 8 chunks of 4096 to keep workspace ~32 MB
#define NCH 8
#define NBc (Bn / NCH)          // 4096 b per chunk
#define PPB 8                   // pairs per block in k_edge
#define RB2 8                   // b per block in k_stqt (40 E-rows)
#define RB3 16                  // b per block in k_inp
#define RB4 16                  // b per block in k_att

// ---------------------------------------------------------------------------
// ws layout (floats):
//   [0, 458752)          : 7 transposed weights WT[m][e][h]
//                          slot0: (Wh-Wsh)^T  slot1: (Wv-Wsv)^T
//                          slot2: Wsh^T  slot3: Wsv^T  slot4: We^T
//                          slot5: Win^T  slot6: Wctx^T
//   [458752, 688128)     : att[b][l]  (full B)
//   [688128, 688142)     : S[7], logS[7]
//   [688144, 5931024)    : Ec  — edge chunk, (NBc*5) x 256
//   [5931024, 6979600)   : qtc — qt chunk,  NBc x 256
//   [6979600, 8028176)   : inpc — inp chunk, NBc x 256
// total ~32.1 MB (same as round 6)
// ---------------------------------------------------------------------------

__device__ __forceinline__ uint32_t rotl32(uint32_t x, int d) {
  return (x << d) | (x >> (32 - d));
}

// JAX threefry2x32, 20 rounds (matches jax/_src/prng.py)
__device__ __forceinline__ void threefry2x32(uint32_t k0, uint32_t k1,
                                             uint32_t x0, uint32_t x1,
                                             uint32_t& o0, uint32_t& o1) {
  uint32_t k2 = k0 ^ k1 ^ 0x1BD11BDAu;
  x0 += k0; x1 += k1;
  x0 += x1; x1 = rotl32(x1, 13); x1 ^= x0;
  x0 += x1; x1 = rotl32(x1, 15); x1 ^= x0;
  x0 += x1; x1 = rotl32(x1, 26); x1 ^= x0;
  x0 += x1; x1 = rotl32(x1,  6); x1 ^= x0;
  x0 += k1; x1 += k2 + 1u;
  x0 += x1; x1 = rotl32(x1, 17); x1 ^= x0;
  x0 += x1; x1 = rotl32(x1, 29); x1 ^= x0;
  x0 += x1; x1 = rotl32(x1, 16); x1 ^= x0;
  x0 += x1; x1 = rotl32(x1, 24); x1 ^= x0;
  x0 += k2; x1 += k0 + 2u;
  x0 += x1; x1 = rotl32(x1, 13); x1 ^= x0;
  x0 += x1; x1 = rotl32(x1, 15); x1 ^= x0;
  x0 += x1; x1 = rotl32(x1, 26); x1 ^= x0;
  x0 += x1; x1 = rotl32(x1,  6); x1 ^= x0;
  x0 += k0; x1 += k1 + 3u;
  x0 += x1; x1 = rotl32(x1, 17); x1 ^= x0;
  x0 += x1; x1 = rotl32(x1, 29); x1 ^= x0;
  x0 += x1; x1 = rotl32(x1, 16); x1 ^= x0;
  x0 += x1; x1 = rotl32(x1, 24); x1 ^= x0;
  x0 += k1; x1 += k2 + 4u;
  x0 += x1; x1 = rotl32(x1, 13); x1 ^= x0;
  x0 += x1; x1 = rotl32(x1, 15); x1 ^= x0;
  x0 += x1; x1 = rotl32(x1, 26); x1 ^= x0;
  x0 += x1; x1 = rotl32(x1,  6); x1 ^= x0;
  x0 += k2; x1 += k0 + 5u;
  o0 = x0; o1 = x1;
}

// ---------------------------------------------------------------------------
// Transpose weights into ws. Slots 0/1 hold DELTA matrices:
//   slot0 = (Wh - Wsh)^T, slot1 = (Wv - Wsv)^T  (branch-free edge kernel).
// ---------------------------------------------------------------------------
__global__ __launch_bounds__(256) void k_transpose(
    const float* __restrict__ w0, const float* __restrict__ w1,
    const float* __restrict__ w2, const float* __restrict__ w3,
    const float* __restrict__ w4, const float* __restrict__ w5,
    const float* __restrict__ w6, float* __restrict__ dst) {
  int e = blockIdx.x;
  int h = threadIdx.x;
  float v;
  switch (blockIdx.y) {
    case 0: v = w0[h * 256 + e] - w2[h * 256 + e]; break;  // Wh - Wsh
    case 1: v = w1[h * 256 + e] - w3[h * 256 + e]; break;  // Wv - Wsv
    case 2: v = w2[h * 256 + e]; break;                    // Wsh
    case 3: v = w3[h * 256 + e]; break;                    // Wsv
    case 4: v = w4[h * 256 + e]; break;                    // We
    case 5: v = w5[h * 256 + e]; break;                    // Win
    default: v = w6[h * 256 + e]; break;                   // Wctx
  }
  dst[(size_t)blockIdx.y * 65536 + e * 256 + h] = v;
}

// ---------------------------------------------------------------------------
// k_edge: BRANCH-FREE edge computation.
//   aS[p] = eh@Wsh^T + ev@Wsv^T        (always)
//   aD[p] = eh@DWh^T + ev@DWv^T        (delta)
//   edge  = aS + cond * aD             (epilogue only)
// Hot loop is pure FMA over statically-indexed arrays — identical structure
// to k_stqt, which is proven spill-free. The uniform if/else that was inside
// the unrolled p-loop in rounds 0-6 (the spill bomb: ~32-BB CFG with all
// accumulators live across every edge) is GONE.
// Live: 32 weight + 16 acc + 8 cf + 16 transient ~ 85 VGPR.
// ---------------------------------------------------------------------------
__global__ __launch_bounds__(256, 2) void k_edge(
    const float* __restrict__ enc, const int* __restrict__ xes,
    const float* __restrict__ wt, int bbase, float* __restrict__ Eo) {
  const int t = threadIdx.x;
  const int pg0 = blockIdx.x * PPB;      // chunk-local pair base

  __shared__ float x[PPB][2][256];       // 16 KB
  __shared__ int s_off[PPB][2];
  __shared__ float s_cf[PPB];

  if (t < PPB) {
    int pg = pg0 + t;
    int bl = pg / 5;
    int tt = pg - bl * 5;
    int b = bbase + bl;
    int base = (b * Tn + tt) * 3;
    int hi = xes[base], vi = xes[base + 1], tc = xes[base + 2];
    s_off[t][0] = (b * Ln + hi) * En;
    s_off[t][1] = (b * Ln + vi) * En;
    s_cf[t] = (tc == 0) ? 1.0f : 0.0f;
  }
  __syncthreads();

  // cooperative stage: 16 rows, 16 threads/row, 4 float4 each
  {
    int seg = t >> 4, i16 = t & 15;      // seg 0..15
    int p = seg >> 1, w = seg & 1;
    const float* src = enc + s_off[p][w];
    float* dstrow = &x[p][w][0];
#pragma unroll
    for (int q = 0; q < 4; q++)
      *(float4*)&dstrow[i16 * 4 + q * 64] =
          *(const float4*)&src[i16 * 4 + q * 64];
  }
  __syncthreads();

  float cf[PPB];
#pragma unroll
  for (int p = 0; p < PPB; p++) cf[p] = s_cf[p];

  const float* DhT  = wt;                // (Wh-Wsh)^T
  const float* DvT  = wt + 65536;        // (Wv-Wsv)^T
  const float* WshT = wt + 2 * 65536;
  const float* WsvT = wt + 3 * 65536;

  float aS[PPB], aD[PPB];
#pragma unroll
  for (int p = 0; p < PPB; p++) { aS[p] = 0.f; aD[p] = 0.f; }

#pragma unroll 1
  for (int e0 = 0; e0 < En; e0 += 8) {
    float ws1[8], ws2[8], dh[8], dv[8];
#pragma unroll
    for (int j = 0; j < 8; j++) {
      int o = (e0 + j) * 256 + t;
      ws1[j] = WshT[o]; ws2[j] = WsvT[o]; dh[j] = DhT[o]; dv[j] = DvT[o];
    }
#pragma unroll
    for (int p = 0; p < PPB; p++) {
      float4 h0 = *(const float4*)&x[p][0][e0];
      float4 h1 = *(const float4*)&x[p][0][e0 + 4];
      float4 v0 = *(const float4*)&x[p][1][e0];
      float4 v1 = *(const float4*)&x[p][1][e0 + 4];
      float s = aS[p], d = aD[p];
      s += ws1[0]*h0.x; s += ws1[1]*h0.y; s += ws1[2]*h0.z; s += ws1[3]*h0.w;
      s += ws1[4]*h1.x; s += ws1[5]*h1.y; s += ws1[6]*h1.z; s += ws1[7]*h1.w;
      s += ws2[0]*v0.x; s += ws2[1]*v0.y; s += ws2[2]*v0.z; s += ws2[3]*v0.w;
      s += ws2[4]*v1.x; s += ws2[5]*v1.y; s += ws2[6]*v1.z; s += ws2[7]*v1.w;
      d += dh[0]*h0.x;  d += dh[1]*h0.y;  d += dh[2]*h0.z;  d += dh[3]*h0.w;
      d += dh[4]*h1.x;  d += dh[5]*h1.y;  d += dh[6]*h1.z;  d += dh[7]*h1.w;
      d += dv[0]*v0.x;  d += dv[1]*v0.y;  d += dv[2]*v0.z;  d += dv[3]*v0.w;
      d += dv[4]*v1.x;  d += dv[5]*v1.y;  d += dv[6]*v1.z;  d += dv[7]*v1.w;
      aS[p] = s; aD[p] = d;
    }
  }

#pragma unroll
  for (int p = 0; p < PPB; p++)
    Eo[(pg0 + p) * 256 + t] = aS[p] + cf[p] * aD[p];
}

// ---------------------------------------------------------------------------
// k_stqt: M = E @ We^T for 40 rows (8 b x 5 tt); epilogue st/qt.  (unchanged)
// ---------------------------------------------------------------------------
__global__ __launch_bounds__(256, 2) void k_stqt(
    const float* __restrict__ E, const float* __restrict__ wt,
    float* __restrict__ qt) {
  const int t = threadIdx.x;
  const int bl0 = blockIdx.x * RB2;

  __shared__ float xe[RB2 * 5][256];     // 40 KB

  {
    const float4* src = (const float4*)(E + bl0 * 5 * 256);
    float4* dst = (float4*)&xe[0][0];
#pragma unroll
    for (int k = 0; k < 10; k++) dst[t + k * 256] = src[t + k * 256];
  }
  __syncthreads();

  const float* WeT = wt + 4 * 65536;
  float m[5][RB2];
#pragma unroll
  for (int i = 0; i < 5; i++)
#pragma unroll
    for (int r = 0; r < RB2; r++) m[i][r] = 0.f;

#pragma unroll 1
  for (int e0 = 0; e0 < En; e0 += 8) {
    float w8[8];
#pragma unroll
    for (int j = 0; j < 8; j++) w8[j] = WeT[(e0 + j) * 256 + t];
#pragma unroll
    for (int tt = 0; tt < 5; tt++) {
#pragma unroll
      for (int r = 0; r < RB2; r++) {
        const float* xb = &xe[r * 5 + tt][e0];
        float4 xa = *(const float4*)(xb);
        float4 xc = *(const float4*)(xb + 4);
        float s = m[tt][r];
        s += w8[0]*xa.x; s += w8[1]*xa.y; s += w8[2]*xa.z; s += w8[3]*xa.w;
        s += w8[4]*xc.x; s += w8[5]*xc.y; s += w8[6]*xc.z; s += w8[7]*xc.w;
        m[tt][r] = s;
      }
    }
  }

#pragma unroll
  for (int r = 0; r < RB2; r++) {
    float s = fmaxf(fmaxf(fmaxf(m[0][r], m[1][r]), fmaxf(m[2][r], m[3][r])),
                    m[4][r]);
    s = fmaxf(s, 0.f);
    float e4 = xe[r * 5 + 4][t];         // per-lane, own t
    qt[(bl0 + r) * 256 + t] = fmaxf(e4 + s, 0.f);
  }
}

// ---------------------------------------------------------------------------
// k_inp: inp = qt @ Win^T + b_in for RB3 b's.  (unchanged)
// ---------------------------------------------------------------------------
__global__ __launch_bounds__(256, 2) void k_inp(
    const float* __restrict__ qt, const float* __restrict__ wt,
    const float* __restrict__ b_in, float* __restrict__ inp) {
  const int t = threadIdx.x;
  const int bl0 = blockIdx.x * RB3;

  __shared__ float xq[RB3][256];         // 16 KB
  {
    const float4* src = (const float4*)(qt + bl0 * 256);
    float4* dst = (float4*)&xq[0][0];
#pragma unroll
    for (int k = 0; k < 4; k++) dst[t + k * 256] = src[t + k * 256];
  }
  __syncthreads();

  const float* WinT = wt + 5 * 65536;
  float a[RB3];
#pragma unroll
  for (int r = 0; r < RB3; r++) a[r] = 0.f;

#pragma unroll 1
  for (int e0 = 0; e0 < En; e0 += 8) {
    float w8[8];
#pragma unroll
    for (int j = 0; j < 8; j++) w8[j] = WinT[(e0 + j) * 256 + t];
#pragma unroll
    for (int r = 0; r < RB3; r++) {
      const float* xb = &xq[r][e0];
      float4 xa = *(const float4*)(xb);
      float4 xc = *(const float4*)(xb + 4);
      float s = a[r];
      s += w8[0]*xa.x; s += w8[1]*xa.y; s += w8[2]*xa.z; s += w8[3]*xa.w;
      s += w8[4]*xc.x; s += w8[5]*xc.y; s += w8[6]*xc.z; s += w8[7]*xc.w;
      a[r] = s;
    }
  }
  float bi = b_in[t];
#pragma unroll
  for (int r = 0; r < RB3; r++)
    inp[(bl0 + r) * 256 + t] = a[r] + bi;
}

// ---------------------------------------------------------------------------
// k_att: per l: ctx = enc[b,l,:] @ Wctx^T; att = sum_h V*tanh(inp+b_ctx+ctx),
// mask, 10*tanh.  (unchanged)
// ---------------------------------------------------------------------------
__global__ __launch_bounds__(256, 2) void k_att(
    const float* __restrict__ enc, const float* __restrict__ inp,
    const int* __restrict__ maskp, const float* __restrict__ wt,
    const float* __restrict__ b_ctx, const float* __restrict__ V,
    int bbase, float* __restrict__ att_out) {
  const int t = threadIdx.x;
  const int bl0 = blockIdx.x * RB4;

  __shared__ float xc[RB4][256];         // 16 KB
  __shared__ float red[4][RB4];

  float ip[RB4];
#pragma unroll
  for (int r = 0; r < RB4; r++) ip[r] = inp[(bl0 + r) * 256 + t];

  const float* WctxT = wt + 6 * 65536;
  const float Vt = V[t];
  const float bc = b_ctx[t];
  const int lane = t & 63, wid = t >> 6;

#pragma unroll 1
  for (int l = 0; l < Ln; l++) {
    {
      int seg = t >> 4, i16 = t & 15;
      const float* src = enc + ((size_t)(bbase + bl0 + seg) * Ln + l) * En;
      float* dstrow = &xc[seg][0];
#pragma unroll
      for (int q = 0; q < 4; q++)
        *(float4*)&dstrow[i16 * 4 + q * 64] =
            *(const float4*)&src[i16 * 4 + q * 64];
    }
    __syncthreads();

    float cx[RB4];
#pragma unroll
    for (int r = 0; r < RB4; r++) cx[r] = 0.f;

#pragma unroll 1
    for (int e0 = 0; e0 < En; e0 += 8) {
      float w8[8];
#pragma unroll
      for (int j = 0; j < 8; j++) w8[j] = WctxT[(e0 + j) * 256 + t];
#pragma unroll
      for (int r = 0; r < RB4; r++) {
        const float* xb = &xc[r][e0];
        float4 xa = *(const float4*)(xb);
        float4 xq = *(const float4*)(xb + 4);
        float s = cx[r];
        s += w8[0]*xa.x; s += w8[1]*xa.y; s += w8[2]*xa.z; s += w8[3]*xa.w;
        s += w8[4]*xq.x; s += w8[5]*xq.y; s += w8[6]*xq.z; s += w8[7]*xq.w;
        cx[r] = s;
      }
    }

    float v8[RB4];
#pragma unroll
    for (int r = 0; r < RB4; r++) v8[r] = Vt * tanhf(ip[r] + bc + cx[r]);
#pragma unroll
    for (int off = 32; off > 0; off >>= 1) {
#pragma unroll
      for (int r = 0; r < RB4; r++) v8[r] += __shfl_down(v8[r], off, 64);
    }
    if (lane == 0) {
#pragma unroll
      for (int r = 0; r < RB4; r++) red[wid][r] = v8[r];
    }
    __syncthreads();
    if (t < RB4) {
      float a = red[0][t] + red[1][t] + red[2][t] + red[3][t];
      int b = bbase + bl0 + t;
      if (!maskp[b * Ln + l]) a = NEGF;
      a = 10.f * tanhf(a);
      att_out[b * Ln + l] = a;
    }
    __syncthreads();
  }
}

// ---------------------------------------------------------------------------
// Column sums for softmax over axis 0 (fp64 accumulation).
// ---------------------------------------------------------------------------
__global__ __launch_bounds__(256) void k_colsum(const float* __restrict__ att,
                                                float* __restrict__ sbuf) {
  int l = blockIdx.x;
  int t = threadIdx.x;
  double s = 0.0;
  for (int b = t; b < Bn; b += 256) s += exp((double)att[b * Ln + l]);
  __shared__ double sd[256];
  sd[t] = s;
  __syncthreads();
  for (int k = 128; k > 0; k >>= 1) {
    if (t < k) sd[t] += sd[t + k];
    __syncthreads();
  }
  if (t == 0) {
    sbuf[l] = (float)sd[0];
    sbuf[7 + l] = (float)log(sd[0]);
  }
}

// ---------------------------------------------------------------------------
// Gumbel-argmax sampling (threefry, partitionable bit-stream) + outputs.
// out = [idx(B) | p(B) | new_mask(B*7)] as float32.
// ---------------------------------------------------------------------------
__global__ __launch_bounds__(256) void k_sample(const float* __restrict__ att,
                                                const float* __restrict__ sbuf,
                                                const int* __restrict__ maskp,
                                                float* __restrict__ out) {
  int b = blockIdx.x * 256 + threadIdx.x;
  if (b >= Bn) return;
  float best = -3.0e38f;
  int bi = 0;
#pragma unroll
  for (int l = 0; l < Ln; l++) {
    uint32_t n = (uint32_t)(b * Ln + l);
    uint32_t o0, o1;
    threefry2x32(0u, 42u, 0u, n, o0, o1);
    uint32_t bits = o0 ^ o1;
    uint32_t fb = (bits >> 9) | 0x3f800000u;
    float f = __uint_as_float(fb) - 1.0f;
    float u = fmaxf(f, 1.1754943508222875e-38f);
    float g = -logf(-logf(u));
    float y = att[b * Ln + l] - sbuf[7 + l] + g;
    if (y > best) { best = y; bi = l; }
  }
  out[b] = (float)bi;
  out[Bn + b] = expf(att[b * Ln + bi] - sbuf[7 + bi]);
#pragma unroll
  for (int l = 0; l < Ln; l++)
    out[2 * Bn + b * Ln + l] = (float)(maskp[b * Ln + l] - ((l == bi) ? 1 : 0));
}

// ---------------------------------------------------------------------------
extern "C" void kernel_launch(void* const* d_in, const int* in_sizes, int n_in,
                              void* d_out, int out_size, void* d_ws,
                              size_t ws_size, hipStream_t stream) {
  const float* enc   = (const float*)d_in[0];
  const int*   xes   = (const int*)d_in[1];
  const int*   maskp = (const int*)d_in[2];
  const float* W_h   = (const float*)d_in[3];
  const float* W_v   = (const float*)d_in[4];
  const float* Ws_h  = (const float*)d_in[5];
  const float* Ws_v  = (const float*)d_in[6];
  const float* W_e   = (const float*)d_in[7];
  const float* W_in  = (const float*)d_in[8];
  const float* b_in  = (const float*)d_in[9];
  const float* W_ctx = (const float*)d_in[10];
  const float* b_ctx = (const float*)d_in[11];
  const float* V     = (const float*)d_in[12];

  float* ws   = (float*)d_ws;
  float* wt   = ws;                         // 458752
  float* att  = ws + 458752;                // 229376
  float* sbuf = ws + 688128;                // 14 (pad to 688144)
  float* Ec   = ws + 688144;                // NBc*5*256 = 5242880
  float* qtc  = ws + 5931024;               // NBc*256 = 1048576
  float* inpc = ws + 6979600;               // NBc*256 = 1048576

  dim3 gT(256, 7);
  k_transpose<<<gT, 256, 0, stream>>>(W_h, W_v, Ws_h, Ws_v, W_e, W_in, W_ctx, wt);

  for (int c = 0; c < NCH; c++) {
    int bbase = c * NBc;
    k_edge<<<NBc * 5 / PPB, 256, 0, stream>>>(enc, xes, wt, bbase, Ec);
    k_stqt<<<NBc / RB2, 256, 0, stream>>>(Ec, wt, qtc);
    k_inp<<<NBc / RB3, 256, 0, stream>>>(qtc, wt, b_in, inpc);
    k_att<<<NBc / RB4, 256, 0, stream>>>(enc, inpc, maskp, wt, b_ctx, V,
                                         bbase, att);
  }

  k_colsum<<<7, 256, 0, stream>>>(att, sbuf);
  k_sample<<<Bn / 256, 256, 0, stream>>>(att, sbuf, maskp, (float*)d_out);
}